// Round 1
// baseline (3145.590 us; speedup 1.0000x reference)
//
#include <hip/hip_runtime.h>
#include <math.h>

#define D_MODEL   768
#define N_LAYER   16
#define D_STATE   64
#define HEADDIM   64
#define D_INNER   1536
#define NHEADS    24
#define CONV_DIM  1664
#define D_IN_PROJ 3224
#define SEQLEN    2048
#define CHUNK     256
#define NCHUNK    8
#define VOCAB     32000

typedef short bf16x8 __attribute__((ext_vector_type(8)));
typedef float f32x4 __attribute__((ext_vector_type(4)));

// round-to-nearest-even fp32 -> bf16 (as ushort)
__device__ __forceinline__ ushort f2bf(float f) {
  unsigned u = __float_as_uint(f);
  unsigned r = (u + 0x7FFFu + ((u >> 16) & 1u)) >> 16;
  return (ushort)r;
}

// ---- XOR-swizzled byte offsets for bf16 LDS tiles (16B slot granularity) ----
// [.][64]-short rows (128B): slot ^= row&7  -> ds_read_b128 conflict-free
__device__ __forceinline__ int sw128(int row, int col) {
  return row * 128 + (((col >> 3) ^ (row & 7)) << 4) + ((col & 7) << 1);
}
// [.][256]-short rows (512B): slot ^= row&7
__device__ __forceinline__ int sw512(int row, int col) {
  return row * 512 + ((((col >> 3) ^ (row & 7)) & 31) << 4) + ((col & 7) << 1);
}
// [.][32]-short rows (64B): slot ^= row&3
__device__ __forceinline__ int sw64(int row, int col) {
  return row * 64 + (((col >> 3) ^ (row & 3)) << 4) + ((col & 7) << 1);
}

// ---------------- reduction helper (blockDim == 256) ----------------
__device__ __forceinline__ float block_sum(float v, float* red) {
#pragma unroll
  for (int off = 32; off > 0; off >>= 1) v += __shfl_down(v, off, 64);
  int wave = threadIdx.x >> 6;
  if ((threadIdx.x & 63) == 0) red[wave] = v;
  __syncthreads();
  return red[0] + red[1] + red[2] + red[3];
}

// ---------------- embedding gather ----------------
__global__ void embed_kernel(const int* __restrict__ ids, const float* __restrict__ emb,
                             float* __restrict__ x) {
  int t = blockIdx.x;
  int id = ids[t];
  const float* src = emb + (size_t)id * D_MODEL;
  float* dst = x + (size_t)t * D_MODEL;
  for (int i = threadIdx.x; i < D_MODEL; i += 256) dst[i] = src[i];
}

// ---------------- fp32 -> bf16 weight conversion with row zero-padding ----------------
__global__ void cvt_w_kernel(const float* __restrict__ src, ushort* __restrict__ dst,
                             int rows, int cols, int total_quads) {
  int i = blockIdx.x * 256 + threadIdx.x;
  if (i >= total_quads) return;
  int e = i * 4;
  int r = e / cols;
  ushort4 o;
  if (r < rows) {
    float4 v = *(const float4*)(src + e);
    o = make_ushort4(f2bf(v.x), f2bf(v.y), f2bf(v.z), f2bf(v.w));
  } else {
    o = make_ushort4(0, 0, 0, 0);
  }
  *(ushort4*)(dst + e) = o;
}

// ---------------- rmsnorm over 768, bf16 output ----------------
__global__ __launch_bounds__(256) void rmsnorm_kernel(const float* __restrict__ x,
                                                      const float* __restrict__ w,
                                                      ushort* __restrict__ out) {
  __shared__ float red[4];
  int t = blockIdx.x;
  int tid = threadIdx.x;
  const float* row = x + (size_t)t * D_MODEL;
  float v0 = row[tid], v1 = row[tid + 256], v2 = row[tid + 512];
  float ss = block_sum(v0 * v0 + v1 * v1 + v2 * v2, red);
  float sc = rsqrtf(ss / (float)D_MODEL + 1e-6f);
  ushort* o = out + (size_t)t * D_MODEL;
  o[tid] = f2bf(v0 * sc * w[tid]);
  o[tid + 256] = f2bf(v1 * sc * w[tid + 256]);
  o[tid + 512] = f2bf(v2 * sc * w[tid + 512]);
}

// ---------------- bf16 MFMA GEMM: C[M,N] = A[M,K] * B[N,K]^T (+R) ----------------
template <int ADD>
__global__ __launch_bounds__(256) void gemm_mfma_kernel(const ushort* __restrict__ A,
                                                        const ushort* __restrict__ B,
                                                        const float* __restrict__ R,
                                                        float* __restrict__ C,
                                                        int N, int K) {
  __shared__ ushort Asm[128 * 32];
  __shared__ ushort Bsm[128 * 32];
  const int bm = blockIdx.y * 128, bn = blockIdx.x * 128;
  const int t = threadIdx.x;
  const int lane = t & 63;
  const int wave = t >> 6;
  const int wm = (wave & 1) * 64, wn = (wave >> 1) * 64;
  const int rl = lane & 15, quad = lane >> 4;

  const int ci0 = t, ci1 = t + 256;
  const int r0 = ci0 >> 2, q0 = (ci0 & 3) ^ ((r0 >> 1) & 3);
  const int r1 = ci1 >> 2, q1 = (ci1 & 3) ^ ((r1 >> 1) & 3);
  const ushort* Ag0 = A + (size_t)(bm + r0) * K + q0 * 8;
  const ushort* Ag1 = A + (size_t)(bm + r1) * K + q1 * 8;
  const ushort* Bg0 = B + (size_t)(bn + r0) * K + q0 * 8;
  const ushort* Bg1 = B + (size_t)(bn + r1) * K + q1 * 8;
  ushort* Al0 = Asm + ci0 * 8;
  ushort* Al1 = Asm + ci1 * 8;
  ushort* Bl0 = Bsm + ci0 * 8;
  ushort* Bl1 = Bsm + ci1 * 8;

  int aoff[4], boff[4];
#pragma unroll
  for (int i = 0; i < 4; i++) {
    int ra = wm + i * 16 + rl;
    aoff[i] = ra * 32 + (quad ^ ((ra >> 1) & 3)) * 8;
    int rb = wn + i * 16 + rl;
    boff[i] = rb * 32 + (quad ^ ((rb >> 1) & 3)) * 8;
  }

  f32x4 acc[4][4];
#pragma unroll
  for (int i = 0; i < 4; i++)
#pragma unroll
    for (int j = 0; j < 4; j++) acc[i][j] = (f32x4)(0.f);

  for (int k0 = 0; k0 < K; k0 += 32) {
    __builtin_amdgcn_global_load_lds(
        (const __attribute__((address_space(1))) void*)(Ag0 + k0),
        (__attribute__((address_space(3))) void*)Al0, 16, 0, 0);
    __builtin_amdgcn_global_load_lds(
        (const __attribute__((address_space(1))) void*)(Ag1 + k0),
        (__attribute__((address_space(3))) void*)Al1, 16, 0, 0);
    __builtin_amdgcn_global_load_lds(
        (const __attribute__((address_space(1))) void*)(Bg0 + k0),
        (__attribute__((address_space(3))) void*)Bl0, 16, 0, 0);
    __builtin_amdgcn_global_load_lds(
        (const __attribute__((address_space(1))) void*)(Bg1 + k0),
        (__attribute__((address_space(3))) void*)Bl1, 16, 0, 0);
    __syncthreads();
    bf16x8 a[4], b[4];
#pragma unroll
    for (int i = 0; i < 4; i++) a[i] = *(const bf16x8*)(Asm + aoff[i]);
#pragma unroll
    for (int j = 0; j < 4; j++) b[j] = *(const bf16x8*)(Bsm + boff[j]);
#pragma unroll
    for (int i = 0; i < 4; i++)
#pragma unroll
      for (int j = 0; j < 4; j++)
        acc[i][j] = __builtin_amdgcn_mfma_f32_16x16x32_bf16(a[i], b[j], acc[i][j], 0, 0, 0);
    __syncthreads();
  }

#pragma unroll
  for (int mt = 0; mt < 4; mt++) {
#pragma unroll
    for (int reg = 0; reg < 4; reg++) {
      int row = bm + wm + mt * 16 + quad * 4 + reg;
      size_t rb = (size_t)row * N;
#pragma unroll
      for (int nt = 0; nt < 4; nt++) {
        int col = bn + wn + nt * 16 + rl;
        if (col < N) {
          float v = acc[mt][nt][reg];
          if (ADD) v += R[rb + col];
          C[rb + col] = v;
        }
      }
    }
  }
}

// ---------------- fused dt(softplus) + per-(chunk,head) inclusive cumsum ----------------
__global__ __launch_bounds__(256) void dt_cumsum_kernel(const float* __restrict__ zx,
                                                        const float* __restrict__ dtb,
                                                        const float* __restrict__ alog,
                                                        float* __restrict__ dt,
                                                        float* __restrict__ cum) {
  int c = blockIdx.x, h = blockIdx.y;
  int s = threadIdx.x;
  int l = c * CHUNK + s;
  float x = zx[(size_t)l * D_IN_PROJ + (D_IN_PROJ - NHEADS) + h] + dtb[h];
  float d = (x > 20.f) ? x : log1pf(expf(x));
  dt[l * NHEADS + h] = d;
  float dA = -d * expf(alog[h]);
  __shared__ float sc[256];
  sc[s] = dA;
  __syncthreads();
  for (int off = 1; off < 256; off <<= 1) {
    float t = (s >= off) ? sc[s - off] : 0.f;
    __syncthreads();
    sc[s] += t;
    __syncthreads();
  }
  cum[h * SEQLEN + c * CHUNK + s] = sc[s];
}

// ---------------- causal depthwise conv (k=4) + silu ----------------
__global__ void conv_silu_kernel(const float* __restrict__ zx, const float* __restrict__ w,
                                 const float* __restrict__ b, float* __restrict__ out) {
  int idx = blockIdx.x * 256 + threadIdx.x;
  if (idx >= SEQLEN * CONV_DIM) return;
  int l = idx / CONV_DIM, ch = idx % CONV_DIM;
  const float* col = zx + D_INNER + ch;
  float acc = b[ch];
#pragma unroll
  for (int k = 0; k < 4; k++) {
    int t = l - 3 + k;
    if (t >= 0) acc += col[(size_t)t * D_IN_PROJ] * w[ch * 4 + k];
  }
  out[idx] = acc / (1.f + expf(-acc));
}

// ---------------- per-chunk local states via MFMA ----------------
// states[p][n] = sum_s (x[s,p]*dt_s*exp(cum_last-cum_s)) * B[s,n]
// A = Xwt[p][s], Bop = Bt[n][s] (both transposed bf16 in LDS), K=256.
__global__ __launch_bounds__(256) void chunk_states_mfma_kernel(
    const float* __restrict__ convout, const float* __restrict__ dt,
    const float* __restrict__ cum, float* __restrict__ lstates) {
  int c = blockIdx.x, h = blockIdx.y;
  __shared__ ushort Bt[64 * 256];
  __shared__ ushort Xwt[64 * 256];
  int t = threadIdx.x;
  float cum_last = cum[h * SEQLEN + c * CHUNK + 255];
  for (int i = 0; i < 16; i++) {
    int f = t + 256 * i;  // 4096 float4 items per matrix
    int s = f >> 4, q0 = (f & 15) * 4;
    int lg = c * CHUNK + s;
    const float* rowp = convout + (size_t)lg * CONV_DIM;
    float wgt = dt[lg * NHEADS + h] * __expf(cum_last - cum[h * SEQLEN + lg]);
    float4 bv = *(const float4*)(rowp + D_INNER + q0);
    float4 xv = *(const float4*)(rowp + h * HEADDIM + q0);
    float ba[4] = {bv.x, bv.y, bv.z, bv.w};
    float xa[4] = {xv.x * wgt, xv.y * wgt, xv.z * wgt, xv.w * wgt};
#pragma unroll
    for (int j = 0; j < 4; j++) {
      *(ushort*)((char*)Bt + sw512(q0 + j, s)) = f2bf(ba[j]);
      *(ushort*)((char*)Xwt + sw512(q0 + j, s)) = f2bf(xa[j]);
    }
  }
  __syncthreads();
  int lane = t & 63, wave = t >> 6;
  int rl = lane & 15, quad = lane >> 4;
  f32x4 acc[4];
#pragma unroll
  for (int nt = 0; nt < 4; nt++) acc[nt] = (f32x4)(0.f);
  for (int ks = 0; ks < 8; ks++) {
    bf16x8 a = *(const bf16x8*)((char*)Xwt + sw512(wave * 16 + rl, ks * 32 + quad * 8));
#pragma unroll
    for (int nt = 0; nt < 4; nt++) {
      bf16x8 b = *(const bf16x8*)((char*)Bt + sw512(nt * 16 + rl, ks * 32 + quad * 8));
      acc[nt] = __builtin_amdgcn_mfma_f32_16x16x32_bf16(a, b, acc[nt], 0, 0, 0);
    }
  }
  float* out = lstates + (size_t)(c * NHEADS + h) * 4096;
#pragma unroll
  for (int nt = 0; nt < 4; nt++)
#pragma unroll
    for (int reg = 0; reg < 4; reg++) {
      int p = wave * 16 + quad * 4 + reg;
      out[p * 64 + nt * 16 + rl] = acc[nt][reg];
    }
}

// ---------------- inter-chunk sequential scan ----------------
__global__ void state_scan_kernel(const float* __restrict__ lstates,
                                  const float* __restrict__ cum,
                                  float* __restrict__ pstates) {
  int h = blockIdx.x;
  int e = blockIdx.y * 256 + threadIdx.x;
  float s = 0.f;
#pragma unroll
  for (int c = 0; c < NCHUNK; c++) {
    pstates[(size_t)(c * NHEADS + h) * 4096 + e] = s;
    float a = expf(cum[h * SEQLEN + c * CHUNK + 255]);
    s = s * a + lstates[(size_t)(c * NHEADS + h) * 4096 + e];
  }
}

// ---------------- Y = (masked-decay CB^T) X + exp(cum) C PS^T + D_skip*xs, via MFMA ----
// Per block (c,h), 4 waves. Wave w owns l-rows [64w, 64w+64).
// GEMM1: S = C·B^T (K=64); decay/mask in fp32; P -> bf16 wave-private LDS;
// GEMM2: Y += P·Xt (K=s); Y_off = C·PS^T scaled by exp(cum_l). No barriers in
// the causal loop (wave-private P + s_waitcnt lgkmcnt(0) per rule #18).
__global__ __launch_bounds__(256) void y_mfma_kernel(
    const float* __restrict__ convout, const float* __restrict__ dt,
    const float* __restrict__ cum, const float* __restrict__ pstates,
    const float* __restrict__ Dskip, float* __restrict__ y) {
  int c = blockIdx.x, h = blockIdx.y;
  __shared__ ushort Cb[256 * 64];   // C rows l, k=n (32 KB)
  __shared__ ushort Bb[256 * 64];   // B rows s, k=n (32 KB)
  __shared__ ushort Xt[64 * 256];   // Xt[p][s] = x[s,p]*dt_s (32 KB)
  __shared__ ushort PSb[64 * 64];   // prev_state[p][n] (8 KB)
  __shared__ ushort Pw[4][64 * 32]; // per-wave P half-tiles (16 KB)
  __shared__ float cumsh[256];
  int t = threadIdx.x;
  int lane = t & 63, wave = t >> 6;

  cumsh[t] = cum[h * SEQLEN + c * CHUNK + t];

  // stage B (cols 0..63 after D_INNER) and C (cols 64..127) rows, bf16 swizzled
  for (int i = 0; i < 32; i++) {
    int f = t + 256 * i;  // 8192 float4 items
    int row = f >> 5, cc = f & 31;
    const float* src = convout + (size_t)(c * CHUNK + row) * CONV_DIM + D_INNER + cc * 4;
    float4 v = *(const float4*)src;
    ushort4 o = make_ushort4(f2bf(v.x), f2bf(v.y), f2bf(v.z), f2bf(v.w));
    int col = (cc & 15) * 4;
    ushort* base = (cc < 16) ? Bb : Cb;
    *(ushort4*)((char*)base + sw128(row, col)) = o;
  }
  // stage Xt transposed, dt folded
  for (int i = 0; i < 16; i++) {
    int f = t + 256 * i;  // 4096 float4 items
    int s = f >> 4, p0 = (f & 15) * 4;
    int lg = c * CHUNK + s;
    const float* src = convout + (size_t)lg * CONV_DIM + h * HEADDIM + p0;
    float4 v = *(const float4*)src;
    float w = dt[lg * NHEADS + h];
    float xa[4] = {v.x * w, v.y * w, v.z * w, v.w * w};
#pragma unroll
    for (int j = 0; j < 4; j++)
      *(ushort*)((char*)Xt + sw512(p0 + j, s)) = f2bf(xa[j]);
  }
  // stage PS
  {
    const float* ps = pstates + (size_t)(c * NHEADS + h) * 4096;
    for (int i = 0; i < 4; i++) {
      int f = t + 256 * i;  // 1024 float4 items
      int e0 = f * 4;
      int p = e0 >> 6, n0 = e0 & 63;
      float4 v = *(const float4*)(ps + e0);
      ushort4 o = make_ushort4(f2bf(v.x), f2bf(v.y), f2bf(v.z), f2bf(v.w));
      *(ushort4*)((char*)PSb + sw128(p, n0)) = o;
    }
  }
  __syncthreads();

  int rl = lane & 15, quad = lane >> 4;
  int wb = wave * 64;
  f32x4 yacc[4][4];
#pragma unroll
  for (int i = 0; i < 4; i++)
#pragma unroll
    for (int pt = 0; pt < 4; pt++) yacc[i][pt] = (f32x4)(0.f);

  // ---- Y_off = C · PS^T ----
#pragma unroll
  for (int kk = 0; kk < 2; kk++) {
    bf16x8 a[4], b[4];
#pragma unroll
    for (int i = 0; i < 4; i++)
      a[i] = *(const bf16x8*)((char*)Cb + sw128(wb + i * 16 + rl, kk * 32 + quad * 8));
#pragma unroll
    for (int pt = 0; pt < 4; pt++)
      b[pt] = *(const bf16x8*)((char*)PSb + sw128(pt * 16 + rl, kk * 32 + quad * 8));
#pragma unroll
    for (int i = 0; i < 4; i++)
#pragma unroll
      for (int pt = 0; pt < 4; pt++)
        yacc[i][pt] = __builtin_amdgcn_mfma_f32_16x16x32_bf16(a[i], b[pt], yacc[i][pt], 0, 0, 0);
  }
  // scale off-part by exp(cum_l)
#pragma unroll
  for (int i = 0; i < 4; i++)
#pragma unroll
    for (int reg = 0; reg < 4; reg++) {
      float el = __expf(cumsh[wb + i * 16 + quad * 4 + reg]);
#pragma unroll
      for (int pt = 0; pt < 4; pt++) yacc[i][pt][reg] *= el;
    }

  // ---- causal diag: s-blocks sb = 0..wave ----
  for (int sb = 0; sb <= wave; sb++) {
#pragma unroll
    for (int half = 0; half < 2; half++) {
      f32x4 sacc[4][2];
#pragma unroll
      for (int i = 0; i < 4; i++)
#pragma unroll
        for (int jj = 0; jj < 2; jj++) sacc[i][jj] = (f32x4)(0.f);
#pragma unroll
      for (int kk = 0; kk < 2; kk++) {
        bf16x8 a[4], b[2];
#pragma unroll
        for (int i = 0; i < 4; i++)
          a[i] = *(const bf16x8*)((char*)Cb + sw128(wb + i * 16 + rl, kk * 32 + quad * 8));
#pragma unroll
        for (int jj = 0; jj < 2; jj++)
          b[jj] = *(const bf16x8*)((char*)Bb +
                                   sw128(sb * 64 + (half * 2 + jj) * 16 + rl, kk * 32 + quad * 8));
#pragma unroll
        for (int i = 0; i < 4; i++)
#pragma unroll
          for (int jj = 0; jj < 2; jj++)
            sacc[i][jj] = __builtin_amdgcn_mfma_f32_16x16x32_bf16(a[i], b[jj], sacc[i][jj], 0, 0, 0);
      }
      // decay+mask -> bf16 -> wave-private P
#pragma unroll
      for (int jj = 0; jj < 2; jj++) {
        int sl = (half * 2 + jj) * 16 + rl;
        int sg = sb * 64 + sl;
        float cs = cumsh[sg];
        int scol = jj * 16 + rl;
#pragma unroll
        for (int i = 0; i < 4; i++)
#pragma unroll
          for (int reg = 0; reg < 4; reg++) {
            int lrow = i * 16 + quad * 4 + reg;
            int ll = wb + lrow;
            float coef = (sg <= ll) ? __expf(cumsh[ll] - cs) : 0.f;
            *(ushort*)((char*)Pw[wave] + sw64(lrow, scol)) = f2bf(sacc[i][jj][reg] * coef);
          }
      }
      asm volatile("s_waitcnt lgkmcnt(0)" ::: "memory");
      __builtin_amdgcn_sched_barrier(0);
      // GEMM2: yacc += P · Xt  (K = 32 this half)
      {
        bf16x8 a2[4], b2[4];
#pragma unroll
        for (int i = 0; i < 4; i++)
          a2[i] = *(const bf16x8*)((char*)Pw[wave] + sw64(i * 16 + rl, quad * 8));
#pragma unroll
        for (int pt = 0; pt < 4; pt++)
          b2[pt] = *(const bf16x8*)((char*)Xt +
                                    sw512(pt * 16 + rl, sb * 64 + half * 32 + quad * 8));
#pragma unroll
        for (int i = 0; i < 4; i++)
#pragma unroll
          for (int pt = 0; pt < 4; pt++)
            yacc[i][pt] = __builtin_amdgcn_mfma_f32_16x16x32_bf16(a2[i], b2[pt], yacc[i][pt], 0, 0, 0);
      }
    }
  }

  // ---- epilogue: += D_skip * xs, store ----
  float dsk = Dskip[h];
#pragma unroll
  for (int i = 0; i < 4; i++)
#pragma unroll
    for (int reg = 0; reg < 4; reg++) {
      int lg = c * CHUNK + wb + i * 16 + quad * 4 + reg;
      const float* xsrow = convout + (size_t)lg * CONV_DIM + h * HEADDIM;
      float* yrow = y + (size_t)lg * D_INNER + h * HEADDIM;
#pragma unroll
      for (int pt = 0; pt < 4; pt++) {
        int p = pt * 16 + rl;
        yrow[p] = yacc[i][pt][reg] + dsk * xsrow[p];
      }
    }
}

// ---------------- gated rmsnorm over 1536, bf16 output ----------------
__global__ __launch_bounds__(256) void gated_rmsnorm_kernel(const float* __restrict__ y,
                                                            const float* __restrict__ zx,
                                                            const float* __restrict__ w,
                                                            ushort* __restrict__ out) {
  __shared__ float red[4];
  int t = blockIdx.x;
  int tid = threadIdx.x;
  const float* yr = y + (size_t)t * D_INNER;
  const float* zr = zx + (size_t)t * D_IN_PROJ;
  float v[6];
  float ss = 0.f;
#pragma unroll
  for (int i = 0; i < 6; i++) {
    int d = tid + i * 256;
    float z = zr[d];
    float val = yr[d] * (z / (1.f + expf(-z)));
    v[i] = val;
    ss += val * val;
  }
  float tot = block_sum(ss, red);
  float sc = rsqrtf(tot / (float)D_INNER + 1e-5f);
  ushort* o = out + (size_t)t * D_INNER;
#pragma unroll
  for (int i = 0; i < 6; i++) {
    int d = tid + i * 256;
    o[d] = f2bf(v[i] * sc * w[d]);
  }
}

// ---------------- launcher ----------------
extern "C" void kernel_launch(void* const* d_in, const int* in_sizes, int n_in,
                              void* d_out, int out_size, void* d_ws, size_t ws_size,
                              hipStream_t stream) {
  const int* ids = (const int*)d_in[0];
  const float* emb = (const float*)d_in[1];
  const float* ln_w = (const float*)d_in[2];
  const float* in_proj_w = (const float*)d_in[3];
  const float* conv_w = (const float*)d_in[4];
  const float* conv_b = (const float*)d_in[5];
  const float* dt_bias = (const float*)d_in[6];
  const float* A_log = (const float*)d_in[7];
  const float* D_skip = (const float*)d_in[8];
  const float* gnorm_w = (const float*)d_in[9];
  const float* out_proj_w = (const float*)d_in[10];
  const float* norm_f_w = (const float*)d_in[11];
  float* logits = (float*)d_out;

  float* ws = (float*)d_ws;
  float* x = ws;                                        // 2048*768
  float* zx = x + (size_t)SEQLEN * D_MODEL;             // 2048*3224
  float* convout = zx + (size_t)SEQLEN * D_IN_PROJ;     // 2048*1664
  float* dt = convout + (size_t)SEQLEN * CONV_DIM;      // 2048*24
  float* cum = dt + SEQLEN * NHEADS;                    // 24*2048
  float* ybuf = cum + SEQLEN * NHEADS;                  // 2048*1536
  float* lstates = ybuf + (size_t)SEQLEN * D_INNER;     // 8*24*64*64
  float* pstates = lstates + (size_t)NCHUNK * NHEADS * HEADDIM * D_STATE;
  ushort* Abf = (ushort*)(pstates + (size_t)NCHUNK * NHEADS * HEADDIM * D_STATE); // 2048*1536 bf16
  ushort* Wbf = Abf + (size_t)SEQLEN * D_INNER;         // 3328*768 bf16 (layer weights, reused)
  ushort* EmbBf = Wbf + (size_t)3328 * D_MODEL;         // 32000*768 bf16

  // one-time per launch: emb -> bf16
  {
    int quads = VOCAB * D_MODEL / 4;
    cvt_w_kernel<<<(quads + 255) / 256, 256, 0, stream>>>(emb, EmbBf, VOCAB, D_MODEL, quads);
  }

  embed_kernel<<<SEQLEN, 256, 0, stream>>>(ids, emb, x);

  for (int i = 0; i < N_LAYER; i++) {
    rmsnorm_kernel<<<SEQLEN, 256, 0, stream>>>(x, ln_w + i * D_MODEL, Abf);
    {
      int quads = 3328 * D_MODEL / 4;
      cvt_w_kernel<<<(quads + 255) / 256, 256, 0, stream>>>(
          in_proj_w + (size_t)i * D_IN_PROJ * D_MODEL, Wbf, D_IN_PROJ, D_MODEL, quads);
    }
    gemm_mfma_kernel<0><<<dim3(26, 16), 256, 0, stream>>>(Abf, Wbf, nullptr, zx,
                                                          D_IN_PROJ, D_MODEL);
    dt_cumsum_kernel<<<dim3(NCHUNK, NHEADS), 256, 0, stream>>>(
        zx, dt_bias + i * NHEADS, A_log + i * NHEADS, dt, cum);
    conv_silu_kernel<<<(SEQLEN * CONV_DIM + 255) / 256, 256, 0, stream>>>(
        zx, conv_w + i * CONV_DIM * 4, conv_b + i * CONV_DIM, convout);
    chunk_states_mfma_kernel<<<dim3(NCHUNK, NHEADS), 256, 0, stream>>>(convout, dt, cum, lstates);
    state_scan_kernel<<<dim3(NHEADS, 16), 256, 0, stream>>>(lstates, cum, pstates);
    y_mfma_kernel<<<dim3(NCHUNK, NHEADS), 256, 0, stream>>>(
        convout, dt, cum, pstates, D_skip + i * NHEADS, ybuf);
    gated_rmsnorm_kernel<<<SEQLEN, 256, 0, stream>>>(ybuf, zx, gnorm_w + i * D_INNER, Abf);
    {
      int quads = D_MODEL * D_INNER / 4;
      cvt_w_kernel<<<(quads + 255) / 256, 256, 0, stream>>>(
          out_proj_w + (size_t)i * D_MODEL * D_INNER, Wbf, D_MODEL, D_INNER, quads);
    }
    gemm_mfma_kernel<1><<<dim3(6, 16), 256, 0, stream>>>(Abf, Wbf, x, x,
                                                         D_MODEL, D_INNER);
  }

  rmsnorm_kernel<<<SEQLEN, 256, 0, stream>>>(x, norm_f_w, Abf);
  gemm_mfma_kernel<0><<<dim3(VOCAB / 128, SEQLEN / 128), 256, 0, stream>>>(
      Abf, EmbBf, nullptr, logits, VOCAB, D_MODEL);
}